// Round 3
// baseline (93.754 us; speedup 1.0000x reference)
//
#include <hip/hip_runtime.h>
#include <math.h>

#define NDIRS 64
#define NBIN 65
#define HIST1 4224             // 66 bins x 64 lanes (bin-major), per wave
#define STAGEF 512             // 64 cells * 8 aggregates per wave (f32)
#define THREADS 256
#define WPB 4
#define SPW 1                  // ONE strip per wave -> write-only flushes
#define NBLK 1024              // 1024*4*1 = 4096 strips
#define ROWF (NDIRS*NBIN)      // 4160 (= bins 0..64 x 64 dirs, bin-major)
#define MROWS 64               // rows after reduceA

static constexpr float INV = 0.28867513459481287f; // 1/(2*sqrt(3))

__global__ __launch_bounds__(THREADS) void wect_hist(
    const float* __restrict__ x, const float* __restrict__ dirs,
    float* __restrict__ accum) {
  __shared__ float hist[WPB * HIST1];     // 67,584 B  (bin-major per wave)
  __shared__ float stage[WPB * STAGEF];   //  8,192 B  (75.8 KB -> 2 blocks/CU)
  const int tid = threadIdx.x;
  const int lane = tid & 63;
  const int wid  = tid >> 6;

  float4* h4 = (float4*)hist;
  for (int idx = tid; idx < WPB * HIST1 / 4; idx += THREADS)
    h4[idx] = make_float4(0.f, 0.f, 0.f, 0.f);
  __syncthreads();

  // lane = DIRECTION constants (pre-scaled by 1/dh)
  const float D0 = dirs[3*lane+0] * INV;
  const float D1 = dirs[3*lane+1] * INV;
  const float D2 = dirs[3*lane+2] * INV;
  const float Q1 = fmaxf(D0, 0.f);
  const float Q2 = fmaxf(D1, 0.f);
  const float Q3 = fmaxf(D2, 0.f);
  const float Q4 = Q2 + Q3;
  const float Q5 = Q1 + Q3;
  const float Q6 = Q1 + Q2;
  const float Q7 = Q1 + Q2 + Q3;

  // bin-major: address = bin*64 + lane -> bank = lane%32 (2-way = free),
  // INDEPENDENT of bin: conflict-free for reads and writes.
  float* __restrict__ myh = hist + wid * HIST1 + lane;
  float4* __restrict__ mystage = (float4*)(stage + wid * STAGEF);

  {
    const int strip = blockIdx.x * WPB + wid;   // [0,4096), ONE per wave
    const int i = strip >> 6, j = strip & 63;
    const int l = lane;                       // lane = CELL for load phase
    const float* p = x + (strip << 6) + l;
    const int dL = (l < 63) ? 1 : 0;
    const int dJ = (j < 63) ? 64 : 0;
    const int dI = (i < 63) ? 4096 : 0;
    const bool iv = dI != 0, jv = dJ != 0, lv = dL != 0;

    const float x000 = p[0],       x001 = p[dL];
    const float x010 = p[dJ],      x011 = p[dJ+dL];
    const float x100 = p[dI],      x101 = p[dI+dL];
    const float x110 = p[dI+dJ],   x111 = p[dI+dJ+dL];

    const float e0m = fmaxf(x000, x100);
    const float e1m = fmaxf(x000, x010);
    const float e2m = fmaxf(x000, x001);
    const float s12 = fmaxf(fmaxf(e1m, x001), x011);
    const float s02 = fmaxf(fmaxf(e0m, x001), x101);
    const float s01 = fmaxf(fmaxf(e0m, x010), x110);
    const float cc  = fmaxf(fmaxf(s01, fmaxf(x001, x101)), fmaxf(x011, x111));

    const float v1 = iv ? -e0m : 0.f;
    const float v2 = jv ? -e1m : 0.f;
    const float v3 = lv ? -e2m : 0.f;
    const float v4 = (jv && lv) ? s12 : 0.f;
    const float v5 = (iv && lv) ? s02 : 0.f;
    const float v6 = (iv && jv) ? s01 : 0.f;
    const float v7 = (iv && jv && lv) ? -cc : 0.f;
    const float T  = x000 + v1+v2+v3+v4+v5+v6+v7;

    // stage this wave's 64 cells' aggregates: 2x ds_write_b128 per lane
    mystage[2*lane]     = make_float4(T,  v1, v2, v3);
    mystage[2*lane + 1] = make_float4(v4, v5, v6, v7);

    const float u0 = (float)i * D0 + (float)j * D1;   // per-lane(dir)

    // Run-length accumulation with WRITE-ONLY flushes:
    // u(t) = u0 + t*D2, |D2| <= 0.289 -> bin ib = ceil(u)+32 is MONOTONE,
    // steps by at most +-1, and (with ONE strip per wave) each flushed bin
    // is visited exactly once per lane. hist is pre-zeroed, so a flush is a
    // pure ds_write_b32 (no read, no +=): zero loop-carried LDS dependency.
    // Final pair {bprev, bprev+1} is provably disjoint from the run's
    // flushed bins (incr run flushes {b0..bprev-1}; decr {b0+1..bprev+2}).
    int   bprev = (int)ceilf(u0) + 32;      // == ib(t=0), in [1,64]
    float r0 = 0.f, r1 = 0.f;               // sums for bins (bprev, bprev+1)

    #pragma unroll 8
    for (int t = 0; t < 64; ++t) {
      const float4 A = mystage[2*t];      // T, v1, v2, v3 (same-addr broadcast)
      const float4 B = mystage[2*t + 1];  // v4, v5, v6, v7
      const float u  = fmaf((float)t, D2, u0);
      const float bf = ceilf(u);
      const float fr = bf - u;                 // [0,1)
      const int   ib = (int)bf + 32;           // provably in [1,64]
      float S = 0.f;
      S += (Q1 > fr) ? A.y : 0.f;
      S += (Q2 > fr) ? A.z : 0.f;
      S += (Q3 > fr) ? A.w : 0.f;
      S += (Q4 > fr) ? B.x : 0.f;
      S += (Q5 > fr) ? B.y : 0.f;
      S += (Q6 > fr) ? B.z : 0.f;
      S += (Q7 > fr) ? B.w : 0.f;

      if (ib != bprev) {                       // exec-masked, store-only body
        const bool up = (ib > bprev);          // step is exactly +-1
        myh[((up ? bprev : (bprev + 1)) << 6)] = up ? r0 : r1;  // pure store
        const float n0 = up ? r1 : 0.f;        // shift the register window
        const float n1 = up ? 0.f : r0;
        r0 = n0; r1 = n1;
      }
      bprev = ib;
      r0 += A.x - S;
      r1 += S;
    }
    // flush the final pair (bprev in [1,64] -> bprev+1 <= 65 = guard bin)
    float* a0 = myh + (bprev << 6);
    a0[0]  = r0;                               // pure stores: bins untouched
    a0[64] = r1;                               // by the run, hist pre-zeroed
  }

  __syncthreads();
  // flush: direct z-index sum of the 4 copies (guard bin 65 >= 4160 excluded);
  // accum stays bin-major [bin*64 + dir]; plain private-row stores (no atomics)
  float* __restrict__ obase = accum + blockIdx.x * ROWF;
  for (int z = tid; z < ROWF; z += THREADS)
    obase[z] = hist[z] + hist[HIST1 + z]
             + hist[2*HIST1 + z] + hist[3*HIST1 + z];
}

// 1024 partial rows -> 64 rows; one output element per thread, coalesced
__global__ __launch_bounds__(256) void wect_reduceA(
    const float* __restrict__ accum, float* __restrict__ mid) {
  const int q = blockIdx.x * 256 + threadIdx.x;    // [0, 64*4160)
  if (q >= MROWS * ROWF) return;
  const int g = q / ROWF, z = q - g * ROWF;
  float v = 0.f;
  #pragma unroll
  for (int m = 0; m < NBLK / MROWS; ++m)           // 16 rows each
    v += accum[(g * (NBLK / MROWS) + m) * ROWF + z];
  mid[g * ROWF + z] = v;
}

__global__ __launch_bounds__(512) void wect_scan(
    const float* __restrict__ mid, float* __restrict__ out) {
  __shared__ float red[8 * NBIN];
  __shared__ float s[NBIN];
  const int k = blockIdx.x, tid = threadIdx.x;
  // mid is bin-major: element (row r, bin c, dir k) = mid[r*ROWF + c*64 + k]
  for (int z = tid; z < 8 * NBIN; z += 512) {   // 520 items > 512 thr: stride
    const int g = z / NBIN, c = z - g * NBIN;
    float v = 0.f;
    #pragma unroll
    for (int r = g; r < MROWS; r += 8) v += mid[r * ROWF + (c << 6) + k];
    red[z] = v;
  }
  __syncthreads();
  if (tid < NBIN) {
    float v = 0.f;
    #pragma unroll
    for (int gg = 0; gg < 8; ++gg) v += red[gg * NBIN + tid];
    s[tid] = v;
  }
  __syncthreads();
  for (int off = 1; off < NBIN; off <<= 1) {
    float a = 0.f;
    if (tid < NBIN && tid >= off) a = s[tid - off];
    __syncthreads();
    if (tid < NBIN && tid >= off) s[tid] += a;
    __syncthreads();
  }
  if (tid < NBIN) out[k * NBIN + tid] = s[tid];
}

extern "C" void kernel_launch(void* const* d_in, const int* in_sizes, int n_in,
                              void* d_out, int out_size, void* d_ws, size_t ws_size,
                              hipStream_t stream) {
  const float* x = (const float*)d_in[0];
  const float* dirs = (const float*)d_in[1];
  float* out = (float*)d_out;
  float* accum = (float*)d_ws;                 // 1024*4160 floats = 17 MB
  float* mid = accum + NBLK * ROWF;            // 64*4160 floats = 1.06 MB

  wect_hist<<<NBLK, THREADS, 0, stream>>>(x, dirs, accum);
  wect_reduceA<<<(MROWS * ROWF + 255) / 256, 256, 0, stream>>>(accum, mid);
  wect_scan<<<NDIRS, 512, 0, stream>>>(mid, out);
}

// Round 4
// 91.163 us; speedup vs baseline: 1.0284x; 1.0284x over previous
//
#include <hip/hip_runtime.h>
#include <math.h>

#define NDIRS 64
#define NBIN 65
#define WIN 21                 // window bins/lane: span<=20 (63*0.289=18.2) +1 S-slot
#define WROW (WIN*64)          // 1344 floats per wave window
#define STAGEF 512             // 64 cells * 8 aggregates per wave (f32)
#define THREADS 256
#define WPB 4
#define NBLK 1024              // 1024*4 = 4096 strips, ONE per wave
#define ROWF (NDIRS*NBIN)      // 4160 (= bins 0..64 x 64 dirs, bin-major)
#define MROWS 64               // rows after reduceA

static constexpr float INV = 0.28867513459481287f; // 1/(2*sqrt(3))

__global__ __launch_bounds__(THREADS) void wect_hist(
    const float* __restrict__ x, const float* __restrict__ dirs,
    float* __restrict__ accum) {
  __shared__ float histw[WPB * WROW];     // 21,504 B (windowed, bin-major)
  __shared__ float stage[WPB * STAGEF];   //  8,192 B
  __shared__ int   b0s[WPB * 64];         //  1,024 B  (30.7 KB -> 4-5 blk/CU)
  const int tid = threadIdx.x;
  const int lane = tid & 63;
  const int wid  = tid >> 6;

  float4* h4 = (float4*)histw;
  for (int idx = tid; idx < WPB * WROW / 4; idx += THREADS)
    h4[idx] = make_float4(0.f, 0.f, 0.f, 0.f);
  __syncthreads();

  // lane = DIRECTION constants (pre-scaled by 1/dh)
  const float D0 = dirs[3*lane+0] * INV;
  const float D1 = dirs[3*lane+1] * INV;
  const float D2 = dirs[3*lane+2] * INV;
  const float Q1 = fmaxf(D0, 0.f);
  const float Q2 = fmaxf(D1, 0.f);
  const float Q3 = fmaxf(D2, 0.f);
  const float Q4 = Q2 + Q3;
  const float Q5 = Q1 + Q3;
  const float Q6 = Q1 + Q2;
  const float Q7 = Q1 + Q2 + Q3;

  // windowed hist, bin-major: addr = wbin*64 + lane -> bank = lane%32
  // (2-way = free), independent of wbin: conflict-free stores.
  float* __restrict__ myhw = histw + wid * WROW + lane;
  float4* __restrict__ mystage = (float4*)(stage + wid * STAGEF);

  {
    const int strip = blockIdx.x * WPB + wid;   // [0,4096), ONE per wave
    const int i = strip >> 6, j = strip & 63;
    const int l = lane;                       // lane = CELL for load phase
    const float* p = x + (strip << 6) + l;
    const int dL = (l < 63) ? 1 : 0;
    const int dJ = (j < 63) ? 64 : 0;
    const int dI = (i < 63) ? 4096 : 0;
    const bool iv = dI != 0, jv = dJ != 0, lv = dL != 0;

    const float x000 = p[0],       x001 = p[dL];
    const float x010 = p[dJ],      x011 = p[dJ+dL];
    const float x100 = p[dI],      x101 = p[dI+dL];
    const float x110 = p[dI+dJ],   x111 = p[dI+dJ+dL];

    const float e0m = fmaxf(x000, x100);
    const float e1m = fmaxf(x000, x010);
    const float e2m = fmaxf(x000, x001);
    const float s12 = fmaxf(fmaxf(e1m, x001), x011);
    const float s02 = fmaxf(fmaxf(e0m, x001), x101);
    const float s01 = fmaxf(fmaxf(e0m, x010), x110);
    const float cc  = fmaxf(fmaxf(s01, fmaxf(x001, x101)), fmaxf(x011, x111));

    const float v1 = iv ? -e0m : 0.f;
    const float v2 = jv ? -e1m : 0.f;
    const float v3 = lv ? -e2m : 0.f;
    const float v4 = (jv && lv) ? s12 : 0.f;
    const float v5 = (iv && lv) ? s02 : 0.f;
    const float v6 = (iv && jv) ? s01 : 0.f;
    const float v7 = (iv && jv && lv) ? -cc : 0.f;
    const float T  = x000 + v1+v2+v3+v4+v5+v6+v7;

    // stage this wave's 64 cells' aggregates: 2x ds_write_b128 per lane
    mystage[2*lane]     = make_float4(T,  v1, v2, v3);
    mystage[2*lane + 1] = make_float4(v4, v5, v6, v7);

    const float u0 = (float)i * D0 + (float)j * D1;   // per-lane(dir)

    // u(t) = u0 + t*D2, |D2| <= 0.289 -> bin ceil(u)+32 is MONOTONE with
    // step in {-1,0,+1}; total span <= 20 bins. Track the running pair
    // (r0,r1) for window slots (wb, wb+1) and STORE THEM UNCONDITIONALLY
    // every t (ds_write2_b32, fire-and-forget). Last-write-wins: a slot's
    // final write occurs at the last t its pair covers it, which holds the
    // completed sum. Pre-zeroed slots never covered stay 0. No branches,
    // no LDS reads of hist, no loop-carried LDS dependency at all.
    const float u63  = fmaf(63.f, D2, u0);
    const int   base = (int)ceilf(fminf(u0, u63));    // window start (rel)
    b0s[wid * 64 + lane] = base + 32;                 // global start bin

    int   wb = (int)ceilf(u0) - base;       // in [0,19]
    float r0 = 0.f, r1 = 0.f;               // sums for slots (wb, wb+1)

    #pragma unroll 8
    for (int t = 0; t < 64; ++t) {
      const float4 A = mystage[2*t];      // T, v1, v2, v3 (same-addr broadcast)
      const float4 B = mystage[2*t + 1];  // v4, v5, v6, v7
      const float u  = fmaf((float)t, D2, u0);
      const float bf = ceilf(u);
      const float fr = bf - u;                 // [0,1)
      const int   wbn = (int)bf - base;        // in [0,19]
      const int   d   = wbn - wb;              // in {-1,0,+1}
      // shift the register window on bin change (branchless)
      const float r0s = (d == 0) ? r0 : ((d > 0) ? r1 : 0.f);
      const float r1s = (d == 0) ? r1 : ((d > 0) ? 0.f : r0);
      float S = 0.f;
      S += (Q1 > fr) ? A.y : 0.f;
      S += (Q2 > fr) ? A.z : 0.f;
      S += (Q3 > fr) ? A.w : 0.f;
      S += (Q4 > fr) ? B.x : 0.f;
      S += (Q5 > fr) ? B.y : 0.f;
      S += (Q6 > fr) ? B.z : 0.f;
      S += (Q7 > fr) ? B.w : 0.f;
      r0 = r0s + (A.x - S);
      r1 = r1s + S;
      wb = wbn;
      float* a = myhw + (wbn << 6);            // slots wbn, wbn+1 (<=20)
      a[0]  = r0;                              // ds_write2_b32 offset1:64
      a[64] = r1;
    }
  }

  __syncthreads();
  // epilogue: map each wave's 21-bin window into the block's 65x64 row.
  // k = tid&63 is constant per thread -> b0 lookups hoisted; bank = k%32.
  float* __restrict__ obase = accum + blockIdx.x * ROWF;
  const int k = tid & 63;
  const int b00 = b0s[0*64 + k], b01 = b0s[1*64 + k],
            b02 = b0s[2*64 + k], b03 = b0s[3*64 + k];
  for (int z = tid; z < ROWF; z += THREADS) {
    const int c = z >> 6;                      // global bin 0..64
    float v = 0.f;
    const int w0 = c - b00;
    if ((unsigned)w0 < WIN) v += histw[0*WROW + (w0 << 6) + k];
    const int w1 = c - b01;
    if ((unsigned)w1 < WIN) v += histw[1*WROW + (w1 << 6) + k];
    const int w2 = c - b02;
    if ((unsigned)w2 < WIN) v += histw[2*WROW + (w2 << 6) + k];
    const int w3 = c - b03;
    if ((unsigned)w3 < WIN) v += histw[3*WROW + (w3 << 6) + k];
    obase[z] = v;                              // guard bin 65 never read
  }
}

// 1024 partial rows -> 64 rows; one output element per thread, coalesced
__global__ __launch_bounds__(256) void wect_reduceA(
    const float* __restrict__ accum, float* __restrict__ mid) {
  const int q = blockIdx.x * 256 + threadIdx.x;    // [0, 64*4160)
  if (q >= MROWS * ROWF) return;
  const int g = q / ROWF, z = q - g * ROWF;
  float v = 0.f;
  #pragma unroll
  for (int m = 0; m < NBLK / MROWS; ++m)           // 16 rows each
    v += accum[(g * (NBLK / MROWS) + m) * ROWF + z];
  mid[g * ROWF + z] = v;
}

__global__ __launch_bounds__(512) void wect_scan(
    const float* __restrict__ mid, float* __restrict__ out) {
  __shared__ float red[8 * NBIN];
  __shared__ float s[NBIN];
  const int k = blockIdx.x, tid = threadIdx.x;
  // mid is bin-major: element (row r, bin c, dir k) = mid[r*ROWF + c*64 + k]
  for (int z = tid; z < 8 * NBIN; z += 512) {   // 520 items > 512 thr: stride
    const int g = z / NBIN, c = z - g * NBIN;
    float v = 0.f;
    #pragma unroll
    for (int r = g; r < MROWS; r += 8) v += mid[r * ROWF + (c << 6) + k];
    red[z] = v;
  }
  __syncthreads();
  if (tid < NBIN) {
    float v = 0.f;
    #pragma unroll
    for (int gg = 0; gg < 8; ++gg) v += red[gg * NBIN + tid];
    s[tid] = v;
  }
  __syncthreads();
  for (int off = 1; off < NBIN; off <<= 1) {
    float a = 0.f;
    if (tid < NBIN && tid >= off) a = s[tid - off];
    __syncthreads();
    if (tid < NBIN && tid >= off) s[tid] += a;
    __syncthreads();
  }
  if (tid < NBIN) out[k * NBIN + tid] = s[tid];
}

extern "C" void kernel_launch(void* const* d_in, const int* in_sizes, int n_in,
                              void* d_out, int out_size, void* d_ws, size_t ws_size,
                              hipStream_t stream) {
  const float* x = (const float*)d_in[0];
  const float* dirs = (const float*)d_in[1];
  float* out = (float*)d_out;
  float* accum = (float*)d_ws;                 // 1024*4160 floats = 17 MB
  float* mid = accum + NBLK * ROWF;            // 64*4160 floats = 1.06 MB

  wect_hist<<<NBLK, THREADS, 0, stream>>>(x, dirs, accum);
  wect_reduceA<<<(MROWS * ROWF + 255) / 256, 256, 0, stream>>>(accum, mid);
  wect_scan<<<NDIRS, 512, 0, stream>>>(mid, out);
}